// Round 1
// baseline (788.125 us; speedup 1.0000x reference)
//
#include <hip/hip_runtime.h>
#include <math.h>

// Problem constants (B, L, D fixed by the reference)
#define BB 16
#define LL 2048
#define DD 512
#define NF 1025   // rfft bins for L=2048
#define TOPK 4

// ws layout (float offsets). Total ~193 MiB.
static const size_t OFF_XT = 0;                               // x transposed [B][D][L]
static const size_t OFF_GT = OFF_XT + (size_t)BB * DD * LL;   // G transposed [B][D][L]
static const size_t OFF_V  = OFF_GT + (size_t)BB * DD * LL;   // V row-major [B*L][D]
static const size_t OFF_M  = OFF_V  + (size_t)BB * LL * DD;   // M = Wq^T Wk [D][D]
static const size_t OFF_S  = OFF_M  + (size_t)DD * DD;        // spectra [B][NF][2]
static const size_t OFF_W  = OFF_S  + (size_t)BB * NF * 2;    // weights [B][4]
static const size_t OFF_I  = OFF_W  + (size_t)BB * TOPK;      // indices [B][4] (int)

// ---------------------------------------------------------------------------
// Transpose x [B][L][D] -> XT [B][D][L], 32x32 LDS tiles
__global__ __launch_bounds__(256) void k_transpose(const float* __restrict__ in,
                                                   float* __restrict__ out) {
    __shared__ float tile[32][33];
    int tx = threadIdx.x & 31, ty = threadIdx.x >> 5;   // 32 x 8
    int d0 = blockIdx.x * 32, t0 = blockIdx.y * 32, b = blockIdx.z;
    const float* ip = in + (size_t)b * LL * DD;
    float* op = out + (size_t)b * DD * LL;
#pragma unroll
    for (int i = 0; i < 4; i++)
        tile[ty + 8 * i][tx] = ip[(size_t)(t0 + ty + 8 * i) * DD + d0 + tx];
    __syncthreads();
#pragma unroll
    for (int i = 0; i < 4; i++)
        op[(size_t)(d0 + ty + 8 * i) * LL + t0 + tx] = tile[tx][ty + 8 * i];
}

// ---------------------------------------------------------------------------
// M = Wq^T * Wk  (512x512x512).  64x64 tile, 4x4 microtile.
__global__ __launch_bounds__(256) void k_gemm1(const float* __restrict__ Wq,
                                               const float* __restrict__ Wk,
                                               float* __restrict__ Mm) {
    __shared__ float As[16][68];
    __shared__ float Bs[16][68];
    int t = threadIdx.x;
    int tx = t & 15, ty = t >> 4;
    int m0 = blockIdx.x * 64, n0 = blockIdx.y * 64;
    float acc[4][4] = {};
    for (int k0 = 0; k0 < DD; k0 += 16) {
        // A[m][k] = Wq[k][m]  (already k-major in memory -> coalesced in m)
#pragma unroll
        for (int r = 0; r < 4; r++) {
            As[ty][tx + 16 * r] = Wq[(size_t)(k0 + ty) * DD + m0 + tx + 16 * r];
            Bs[ty][tx + 16 * r] = Wk[(size_t)(k0 + ty) * DD + n0 + tx + 16 * r];
        }
        __syncthreads();
#pragma unroll
        for (int k = 0; k < 16; k++) {
            float4 a4 = *(const float4*)&As[k][ty * 4];
            float4 b4 = *(const float4*)&Bs[k][tx * 4];
            float a[4] = {a4.x, a4.y, a4.z, a4.w};
            float b[4] = {b4.x, b4.y, b4.z, b4.w};
#pragma unroll
            for (int i = 0; i < 4; i++)
#pragma unroll
                for (int j = 0; j < 4; j++) acc[i][j] += a[i] * b[j];
        }
        __syncthreads();
    }
#pragma unroll
    for (int i = 0; i < 4; i++) {
        float4 v = make_float4(acc[i][0], acc[i][1], acc[i][2], acc[i][3]);
        *(float4*)&Mm[(size_t)(m0 + ty * 4 + i) * DD + n0 + tx * 4] = v;
    }
}

// ---------------------------------------------------------------------------
// [G | V] = x * [M^T | Wv^T] (+bv on V half).
// 128x128 tile, BK=16, 256 threads, 8x8 microtile (split 4+4 to kill bank conflicts).
// G is written TRANSPOSED into GT[B][D][L]; V row-major.
__global__ __launch_bounds__(256) void k_gemm2(const float* __restrict__ X,
                                               const float* __restrict__ Mm,
                                               const float* __restrict__ Wv,
                                               const float* __restrict__ bv,
                                               float* __restrict__ GT,
                                               float* __restrict__ V) {
    __shared__ float As[16][132];
    __shared__ float Bs[16][132];
    int t = threadIdx.x;
    int tx = t & 15, ty = t >> 4;
    int m0 = blockIdx.x * 128, n0 = blockIdx.y * 128;
    bool isG = (n0 < DD);
    const float* Bbase = isG ? Mm : Wv;
    int nb0 = isG ? n0 : (n0 - DD);
    float acc[8][8] = {};
    int lk = t & 15;       // k lane for staging (contiguous dim)
    int lm = t >> 4;       // row-group 0..15
    for (int k0 = 0; k0 < DD; k0 += 16) {
#pragma unroll
        for (int r = 0; r < 8; r++) {
            As[lk][lm + 16 * r] = X[(size_t)(m0 + lm + 16 * r) * DD + k0 + lk];
            Bs[lk][lm + 16 * r] = Bbase[(size_t)(nb0 + lm + 16 * r) * DD + k0 + lk];
        }
        __syncthreads();
#pragma unroll
        for (int k = 0; k < 16; k++) {
            float a[8], b[8];
            *(float4*)&a[0] = *(const float4*)&As[k][ty * 4];
            *(float4*)&a[4] = *(const float4*)&As[k][ty * 4 + 64];
            *(float4*)&b[0] = *(const float4*)&Bs[k][tx * 4];
            *(float4*)&b[4] = *(const float4*)&Bs[k][tx * 4 + 64];
#pragma unroll
            for (int i = 0; i < 8; i++)
#pragma unroll
                for (int j = 0; j < 8; j++) acc[i][j] += a[i] * b[j];
        }
        __syncthreads();
    }
    int bidx = m0 >> 11;          // batch (128 | 2048)
    int tloc = m0 & 2047;
    if (isG) {
        // write transposed: column d gets 4+4 consecutive t values
#pragma unroll
        for (int j = 0; j < 8; j++) {
            int dcol = n0 + tx * 4 + (j & 3) + ((j >> 2) << 6);
            float* gp = &GT[((size_t)bidx * DD + dcol) * LL + tloc + ty * 4];
            *(float4*)gp        = make_float4(acc[0][j], acc[1][j], acc[2][j], acc[3][j]);
            *(float4*)(gp + 64) = make_float4(acc[4][j], acc[5][j], acc[6][j], acc[7][j]);
        }
    } else {
        int v0 = nb0 + tx * 4;
        float4 blo = *(const float4*)&bv[v0];
        float4 bhi = *(const float4*)&bv[v0 + 64];
#pragma unroll
        for (int i = 0; i < 8; i++) {
            int m = m0 + ty * 4 + (i & 3) + ((i >> 2) << 6);
            float* vp = &V[(size_t)m * DD + v0];
            *(float4*)vp = make_float4(acc[i][0] + blo.x, acc[i][1] + blo.y,
                                       acc[i][2] + blo.z, acc[i][3] + blo.w);
            *(float4*)(vp + 64) = make_float4(acc[i][4] + bhi.x, acc[i][5] + bhi.y,
                                              acc[i][6] + bhi.z, acc[i][7] + bhi.w);
        }
    }
}

// ---------------------------------------------------------------------------
__global__ void k_zero(float* __restrict__ S) {
    int i = blockIdx.x * 256 + threadIdx.x;
    int n = BB * NF * 2;
    for (; i < n; i += gridDim.x * 256) S[i] = 0.f;
}

// ---------------------------------------------------------------------------
// Per (b, 16-channel group): packed complex FFT of z = x_d + i*G_d (Stockham,
// LDS twiddle table), split Hermitian halves, accumulate S += A*conj(Gf).
__global__ __launch_bounds__(256) void k_fft(const float* __restrict__ XT,
                                             const float* __restrict__ GT,
                                             float* __restrict__ S) {
    __shared__ float2 buf[2][2048];
    __shared__ float2 twl[1024];
    __shared__ float2 Sacc[NF];
    int tid = threadIdx.x;
    int grp = blockIdx.x;    // 0..31
    int b = blockIdx.y;      // 0..15
    for (int j = tid; j < 1024; j += 256) {
        float sn, cs;
        sincosf(-6.283185307179586f * (float)j / 2048.0f, &sn, &cs);
        twl[j] = make_float2(cs, sn);
    }
    for (int f = tid; f < NF; f += 256) Sacc[f] = make_float2(0.f, 0.f);
    for (int c = 0; c < 16; c++) {
        int d = grp * 16 + c;
        const float4* xp = (const float4*)(XT + ((size_t)b * DD + d) * LL);
        const float4* gp = (const float4*)(GT + ((size_t)b * DD + d) * LL);
        __syncthreads();   // prev channel's reads of buf done
        for (int i = tid; i < 512; i += 256) {
            float4 xv = xp[i];
            float4 gv = gp[i];
            buf[0][4 * i + 0] = make_float2(xv.x, gv.x);
            buf[0][4 * i + 1] = make_float2(xv.y, gv.y);
            buf[0][4 * i + 2] = make_float2(xv.z, gv.z);
            buf[0][4 * i + 3] = make_float2(xv.w, gv.w);
        }
        __syncthreads();
        int src = 0, m = 1, lmv = 0;
        for (int l = 1024; l >= 1; l >>= 1) {
            for (int w = tid; w < 1024; w += 256) {
                int k = w & (m - 1);
                int jm = w - k;               // j*m
                float2 a = buf[src][k + jm];
                float2 bb = buf[src][k + jm + 1024];
                float2 tw = twl[jm];          // e^{-2pi i (j*m)/2048} = e^{-2pi i j/(2l)}
                float dr = a.x - bb.x, di = a.y - bb.y;
                buf[src ^ 1][k + 2 * jm]     = make_float2(a.x + bb.x, a.y + bb.y);
                buf[src ^ 1][k + 2 * jm + m] = make_float2(dr * tw.x - di * tw.y,
                                                           dr * tw.y + di * tw.x);
            }
            __syncthreads();
            src ^= 1; m <<= 1; lmv++;
        }
        // src == 1 after 11 stages. Split packed FFT + accumulate A*conj(Gf).
        for (int f = tid; f <= 1024; f += 256) {
            float2 p = buf[src][f];
            float2 q = buf[src][(2048 - f) & 2047];
            float ar = 0.5f * (p.x + q.x), ai = 0.5f * (p.y - q.y);
            float dr = p.x - q.x, di = p.y + q.y;
            float gr = 0.5f * di, gi = -0.5f * dr;
            Sacc[f].x += ar * gr + ai * gi;
            Sacc[f].y += ai * gr - ar * gi;
        }
    }
    __syncthreads();
    float* Sg = S + (size_t)b * NF * 2;
    for (int f = tid; f < NF; f += 256) {
        atomicAdd(&Sg[2 * f], Sacc[f].x);
        atomicAdd(&Sg[2 * f + 1], Sacc[f].y);
    }
}

// ---------------------------------------------------------------------------
// Per batch: inverse FFT of Hermitian spectrum -> mean_corr, top-4, softmax.
__global__ __launch_bounds__(256) void k_topk(const float* __restrict__ S,
                                              float* __restrict__ wts,
                                              int* __restrict__ idxs) {
    __shared__ float2 buf[2][2048];
    __shared__ float2 twl[1024];
    __shared__ float cv[2048];
    __shared__ float rv[256];
    __shared__ int ri[256];
    __shared__ float topv[TOPK];
    __shared__ int topi[TOPK];
    int tid = threadIdx.x;
    int b = blockIdx.x;
    const float* Sg = S + (size_t)b * NF * 2;
    for (int j = tid; j < 1024; j += 256) {
        float sn, cs;
        sincosf(6.283185307179586f * (float)j / 2048.0f, &sn, &cs);  // +sign: inverse
        twl[j] = make_float2(cs, sn);
    }
    for (int f = tid; f < 2048; f += 256) {
        float re, im;
        if (f <= 1024) { re = Sg[2 * f]; im = Sg[2 * f + 1]; }
        else { re = Sg[2 * (2048 - f)]; im = -Sg[2 * (2048 - f) + 1]; }
        buf[0][f] = make_float2(re, im);
    }
    __syncthreads();
    int src = 0, m = 1;
    for (int l = 1024; l >= 1; l >>= 1) {
        for (int w = tid; w < 1024; w += 256) {
            int k = w & (m - 1);
            int jm = w - k;
            float2 a = buf[src][k + jm];
            float2 bb = buf[src][k + jm + 1024];
            float2 tw = twl[jm];
            float dr = a.x - bb.x, di = a.y - bb.y;
            buf[src ^ 1][k + 2 * jm]     = make_float2(a.x + bb.x, a.y + bb.y);
            buf[src ^ 1][k + 2 * jm + m] = make_float2(dr * tw.x - di * tw.y,
                                                       dr * tw.y + di * tw.x);
        }
        __syncthreads();
        src ^= 1; m <<= 1;
    }
    const float scale = 1.0f / ((float)LL * (float)DD);   // irfft 1/N and mean 1/D
    for (int f = tid; f < 2048; f += 256) cv[f] = buf[src][f].x * scale;
    __syncthreads();
    for (int r = 0; r < TOPK; r++) {
        float best = -3.0e38f;
        int bi = 0x7fffffff;
        for (int f = tid; f < 2048; f += 256) {
            bool taken = false;
            for (int q = 0; q < r; q++) taken |= (topi[q] == f);
            float v = cv[f];
            if (!taken && (v > best || (v == best && f < bi))) { best = v; bi = f; }
        }
        rv[tid] = best; ri[tid] = bi;
        __syncthreads();
        for (int s = 128; s > 0; s >>= 1) {
            if (tid < s) {
                float v2 = rv[tid + s]; int i2 = ri[tid + s];
                if (v2 > rv[tid] || (v2 == rv[tid] && i2 < ri[tid])) { rv[tid] = v2; ri[tid] = i2; }
            }
            __syncthreads();
        }
        if (tid == 0) { topv[r] = rv[0]; topi[r] = ri[0]; }
        __syncthreads();
    }
    if (tid == 0) {
        float mx = topv[0];
        float e[TOPK], sum = 0.f;
        for (int k = 0; k < TOPK; k++) { e[k] = expf(topv[k] - mx); sum += e[k]; }
        for (int k = 0; k < TOPK; k++) {
            wts[b * TOPK + k] = e[k] / sum;
            idxs[b * TOPK + k] = topi[k];
        }
    }
}

// ---------------------------------------------------------------------------
// out[b,l,:] = sum_k w_k * V[b,(l-idx_k)&2047,:]
__global__ __launch_bounds__(128) void k_agg(const float* __restrict__ V,
                                             const float* __restrict__ wts,
                                             const int* __restrict__ idxs,
                                             float* __restrict__ out) {
    int l = blockIdx.x, b = blockIdx.y;
    int t = threadIdx.x;   // 0..127, float4 over D=512
    const float4* Vb = (const float4*)(V + (size_t)b * LL * DD);
    float4 acc = make_float4(0.f, 0.f, 0.f, 0.f);
#pragma unroll
    for (int k = 0; k < TOPK; k++) {
        float w = wts[b * TOPK + k];
        int r = (l - idxs[b * TOPK + k]) & (LL - 1);
        float4 v = Vb[(size_t)r * 128 + t];
        acc.x += w * v.x; acc.y += w * v.y; acc.z += w * v.z; acc.w += w * v.w;
    }
    ((float4*)out)[((size_t)b * LL + l) * 128 + t] = acc;
}

// ---------------------------------------------------------------------------
extern "C" void kernel_launch(void* const* d_in, const int* in_sizes, int n_in,
                              void* d_out, int out_size, void* d_ws, size_t ws_size,
                              hipStream_t stream) {
    const float* x  = (const float*)d_in[0];
    const float* Wq = (const float*)d_in[1];
    const float* bq = (const float*)d_in[2];
    const float* Wk = (const float*)d_in[3];
    const float* bk = (const float*)d_in[4];
    const float* Wv = (const float*)d_in[5];
    const float* bv = (const float*)d_in[6];
    (void)bq; (void)bk;   // provably cancel: tau-independent shift, softmax shift-invariant
    (void)in_sizes; (void)n_in; (void)out_size; (void)ws_size;

    float* ws  = (float*)d_ws;
    float* XT  = ws + OFF_XT;
    float* GT  = ws + OFF_GT;
    float* V   = ws + OFF_V;
    float* Mm  = ws + OFF_M;
    float* S   = ws + OFF_S;
    float* wts = ws + OFF_W;
    int*   idx = (int*)(ws + OFF_I);
    float* out = (float*)d_out;

    k_transpose<<<dim3(DD / 32, LL / 32, BB), 256, 0, stream>>>(x, XT);
    k_gemm1<<<dim3(DD / 64, DD / 64), 256, 0, stream>>>(Wq, Wk, Mm);
    k_gemm2<<<dim3((BB * LL) / 128, (2 * DD) / 128), 256, 0, stream>>>(x, Mm, Wv, bv, GT, V);
    k_zero<<<32, 256, 0, stream>>>(S);
    k_fft<<<dim3(DD / 16, BB), 256, 0, stream>>>(XT, GT, S);
    k_topk<<<BB, 256, 0, stream>>>(S, wts, idx);
    k_agg<<<dim3(LL, BB), 128, 0, stream>>>(V, wts, idx, out);
}

// Round 2
// 400.370 us; speedup vs baseline: 1.9685x; 1.9685x over previous
//
#include <hip/hip_runtime.h>
#include <math.h>

typedef unsigned short u16;
typedef unsigned int   u32;
typedef __attribute__((ext_vector_type(8))) __bf16 bf16x8;
typedef __attribute__((ext_vector_type(4))) float  f32x4;

#define BB 16
#define LL 2048
#define DD 512
#define NF 1025
#define TOPK 4

// ws layout (float-unit offsets), total ~202.5 MB (same footprint class as round 1)
static const size_t OFF_XB  = 0;                         // bf16 x row-major [B*L][D]   (u16)
static const size_t OFF_XTB = OFF_XB  + 8388608;         // bf16 x transposed [B][D][L] (u16)
static const size_t OFF_GT  = OFF_XTB + 8388608;         // f32 G transposed [B][D][L]
static const size_t OFF_V   = OFF_GT  + 16777216;        // f32 V row-major [B*L][D]
static const size_t OFF_BBM = OFF_V   + 16777216;        // bf16 Bmat [1024][512]: rows 0..511 = M, 512..1023 = Wv
static const size_t OFF_S   = OFF_BBM + 262144;          // spectra [B][NF][2]
static const size_t OFF_W   = OFF_S   + (size_t)BB * NF * 2;
static const size_t OFF_I   = OFF_W   + BB * TOPK;

__device__ __forceinline__ u16 f2bf(float f) {           // RNE, finite inputs
    u32 u = __float_as_uint(f);
    return (u16)((u + 0x7fffu + ((u >> 16) & 1u)) >> 16);
}
__device__ __forceinline__ float bf2f(u16 h) {
    return __uint_as_float(((u32)h) << 16);
}
__device__ __forceinline__ void gload16(const void* g, void* l) {
    __builtin_amdgcn_global_load_lds((const __attribute__((address_space(1))) void*)g,
                                     (__attribute__((address_space(3))) void*)l, 16, 0, 0);
}

// ---------------------------------------------------------------------------
// x fp32 [B][L][D] -> XB bf16 row-major + XTB bf16 transposed [B][D][L]
__global__ __launch_bounds__(256) void k_transpose(const float* __restrict__ in,
                                                   u16* __restrict__ xb,
                                                   u16* __restrict__ xtb) {
    __shared__ u16 tile[32][33];
    int tx = threadIdx.x & 31, ty = threadIdx.x >> 5;
    int d0 = blockIdx.x * 32, t0 = blockIdx.y * 32, b = blockIdx.z;
    const float* ip = in + (size_t)b * LL * DD;
    u16* xbp = xb + (size_t)b * LL * DD;
    u16* xtp = xtb + (size_t)b * DD * LL;
#pragma unroll
    for (int i = 0; i < 4; i++) {
        float v = ip[(size_t)(t0 + ty + 8 * i) * DD + d0 + tx];
        u16 h = f2bf(v);
        xbp[(size_t)(t0 + ty + 8 * i) * DD + d0 + tx] = h;
        tile[ty + 8 * i][tx] = h;
    }
    __syncthreads();
#pragma unroll
    for (int i = 0; i < 4; i++)
        xtp[(size_t)(d0 + ty + 8 * i) * LL + t0 + tx] = tile[tx][ty + 8 * i];
}

// ---------------------------------------------------------------------------
// M = Wq^T * Wk  (512x512x512) fp32 compute -> bf16 rows 0..511 of Bmat
__global__ __launch_bounds__(256) void k_gemm1(const float* __restrict__ Wq,
                                               const float* __restrict__ Wk,
                                               u16* __restrict__ Bm) {
    __shared__ float As[16][68];
    __shared__ float Bs[16][68];
    int t = threadIdx.x;
    int tx = t & 15, ty = t >> 4;
    int m0 = blockIdx.x * 64, n0 = blockIdx.y * 64;
    float acc[4][4] = {};
    for (int k0 = 0; k0 < DD; k0 += 16) {
#pragma unroll
        for (int r = 0; r < 4; r++) {
            As[ty][tx + 16 * r] = Wq[(size_t)(k0 + ty) * DD + m0 + tx + 16 * r];
            Bs[ty][tx + 16 * r] = Wk[(size_t)(k0 + ty) * DD + n0 + tx + 16 * r];
        }
        __syncthreads();
#pragma unroll
        for (int k = 0; k < 16; k++) {
            float4 a4 = *(const float4*)&As[k][ty * 4];
            float4 b4 = *(const float4*)&Bs[k][tx * 4];
            float a[4] = {a4.x, a4.y, a4.z, a4.w};
            float b[4] = {b4.x, b4.y, b4.z, b4.w};
#pragma unroll
            for (int i = 0; i < 4; i++)
#pragma unroll
                for (int j = 0; j < 4; j++) acc[i][j] += a[i] * b[j];
        }
        __syncthreads();
    }
#pragma unroll
    for (int i = 0; i < 4; i++) {
        uint2 o;
        o.x = (u32)f2bf(acc[i][0]) | ((u32)f2bf(acc[i][1]) << 16);
        o.y = (u32)f2bf(acc[i][2]) | ((u32)f2bf(acc[i][3]) << 16);
        *(uint2*)&Bm[(size_t)(m0 + ty * 4 + i) * DD + n0 + tx * 4] = o;
    }
}

// Wv fp32 -> bf16 rows 512..1023 of Bmat
__global__ __launch_bounds__(256) void k_castwv(const float* __restrict__ Wv,
                                                u16* __restrict__ Bm) {
    int i = blockIdx.x * 256 + threadIdx.x;   // 262144 total
    Bm[DD * DD + i] = f2bf(Wv[i]);
}

// ---------------------------------------------------------------------------
// [G | V] = XB * Bmat^T (bf16 MFMA, fp32 acc). m97 recipe: 128x128 tile, BK=64,
// global_load_lds width 16, 2-barrier K-loop. G written transposed (LDS-staged,
// XOR swizzle); V row-major + bias.
__global__ __launch_bounds__(256, 2) void k_gemm2(const u16* __restrict__ Ab,
                                                  const u16* __restrict__ Bm,
                                                  const float* __restrict__ bv,
                                                  float* __restrict__ GT,
                                                  float* __restrict__ V) {
    __shared__ u16 smem[16384];     // As[128*64] | Bs[128*64], reused as 8192-float epilogue buf
    u16* As = smem;
    u16* Bs = smem + 8192;
    int t = threadIdx.x;
    int wave = t >> 6, lane = t & 63;
    int l15 = lane & 15, l4 = lane >> 4;
    int qr = wave & 1, qc = wave >> 1;          // 2x2 64x64 quadrants
    int m0 = blockIdx.x * 128, n0 = blockIdx.y * 128;

    f32x4 acc[4][4];
#pragma unroll
    for (int i = 0; i < 4; i++)
#pragma unroll
        for (int j = 0; j < 4; j++) acc[i][j] = (f32x4){0.f, 0.f, 0.f, 0.f};

    const u16* Ag = Ab + (size_t)m0 * DD;
    const u16* Bg = Bm + (size_t)n0 * DD;
    int a_base = (qr * 64 + l15) * 64 + l4 * 8;
    int b_base = (qc * 64 + l15) * 64 + l4 * 8;

    for (int k0 = 0; k0 < DD; k0 += 64) {
#pragma unroll
        for (int n = 0; n < 4; n++) {
            int c = wave * 256 + n * 64 + lane;       // 16B chunk id 0..1023
            int row = c >> 3, col = (c & 7) * 8;
            gload16(Ag + (size_t)row * DD + k0 + col, (char*)As + (size_t)(wave * 256 + n * 64) * 16);
            gload16(Bg + (size_t)row * DD + k0 + col, (char*)Bs + (size_t)(wave * 256 + n * 64) * 16);
        }
        __syncthreads();              // drains vmcnt -> tiles ready
#pragma unroll
        for (int kk = 0; kk < 64; kk += 32) {
            bf16x8 af[4], bq[4];
#pragma unroll
            for (int i = 0; i < 4; i++) af[i] = *(const bf16x8*)(As + a_base + i * 1024 + kk);
#pragma unroll
            for (int j = 0; j < 4; j++) bq[j] = *(const bf16x8*)(Bs + b_base + j * 1024 + kk);
#pragma unroll
            for (int i = 0; i < 4; i++)
#pragma unroll
                for (int j = 0; j < 4; j++)
                    acc[i][j] = __builtin_amdgcn_mfma_f32_16x16x32_bf16(af[i], bq[j], acc[i][j], 0, 0, 0);
        }
        __syncthreads();              // LDS safe to overwrite
    }

    // Epilogue. C/D layout (m89/m91): col = lane&15, row = (lane>>4)*4 + reg.
    float*  tb  = (float*)smem;
    float4* tb4 = (float4*)smem;
    int bidx = m0 >> 11;
    int tbase = m0 & 2047;
    if (n0 < DD) {
        // G half: write transposed GT[b][n][t], coalesced along t
#pragma unroll
        for (int p = 0; p < 2; p++) {
            __syncthreads();
            if (qc == p) {
#pragma unroll
                for (int j = 0; j < 4; j++) {
                    int nloc = j * 16 + l15;                 // 0..63 within this n-half
#pragma unroll
                    for (int i = 0; i < 4; i++) {
                        int tq = qr * 16 + i * 4 + l4;       // t-chunk (tloc>>2), 0..31
                        tb4[nloc * 32 + (tq ^ (nloc & 31))] = *(float4*)&acc[i][j];
                    }
                }
            }
            __syncthreads();
#pragma unroll
            for (int u = 0; u < 8; u++) {
                int idx4 = u * 256 + t;
                int nloc = idx4 >> 5, c4 = idx4 & 31;
                float4 v = tb4[nloc * 32 + (c4 ^ (nloc & 31))];
                *(float4*)&GT[((size_t)bidx * DD + n0 + p * 64 + nloc) * LL + tbase + c4 * 4] = v;
            }
        }
    } else {
        // V half: row-major + bias, coalesced along n
        int nb = n0 - DD;
#pragma unroll
        for (int p = 0; p < 2; p++) {
            __syncthreads();
            if (qr == p) {
#pragma unroll
                for (int j = 0; j < 4; j++) {
                    int nloc = qc * 64 + j * 16 + l15;       // 0..127
#pragma unroll
                    for (int i = 0; i < 4; i++) {
#pragma unroll
                        for (int r = 0; r < 4; r++) {
                            int mloc = i * 16 + l4 * 4 + r;  // 0..63 within this m-half
                            int nc = ((nloc >> 2) ^ (mloc & 31)) << 2;
                            tb[mloc * 128 + nc + (nloc & 3)] = acc[i][j][r];
                        }
                    }
                }
            }
            __syncthreads();
#pragma unroll
            for (int u = 0; u < 8; u++) {
                int idx4 = u * 256 + t;
                int mloc = idx4 >> 5, c4 = idx4 & 31;
                float4 v = tb4[mloc * 32 + (c4 ^ (mloc & 31))];
                float4 bias = *(const float4*)&bv[nb + c4 * 4];
                v.x += bias.x; v.y += bias.y; v.z += bias.z; v.w += bias.w;
                *(float4*)&V[(size_t)(m0 + p * 64 + mloc) * DD + nb + c4 * 4] = v;
            }
        }
    }
}

// ---------------------------------------------------------------------------
__global__ void k_zero(float* __restrict__ S) {
    int i = blockIdx.x * 256 + threadIdx.x;
    int n = BB * NF * 2;
    for (; i < n; i += gridDim.x * 256) S[i] = 0.f;
}

// ---------------------------------------------------------------------------
// Per (b, 16-channel group): packed complex FFT of z = x_d + i*G_d (Stockham),
// split Hermitian halves, accumulate S += Xf * conj(Gf).
__global__ __launch_bounds__(256) void k_fft(const u16* __restrict__ XTB,
                                             const float* __restrict__ GT,
                                             float* __restrict__ S) {
    __shared__ float2 buf[2][2048];
    __shared__ float2 twl[1024];
    __shared__ float2 Sacc[NF];
    int tid = threadIdx.x;
    int grp = blockIdx.x;    // 0..31
    int b = blockIdx.y;      // 0..15
    for (int j = tid; j < 1024; j += 256) {
        float sn, cs;
        sincosf(-6.283185307179586f * (float)j / 2048.0f, &sn, &cs);
        twl[j] = make_float2(cs, sn);
    }
    for (int f = tid; f < NF; f += 256) Sacc[f] = make_float2(0.f, 0.f);
    for (int c = 0; c < 16; c++) {
        int d = grp * 16 + c;
        const u16*   xp = XTB + ((size_t)b * DD + d) * LL;
        const float* gp = GT  + ((size_t)b * DD + d) * LL;
        __syncthreads();
        for (int i = tid; i < 2048; i += 256)
            buf[0][i] = make_float2(bf2f(xp[i]), gp[i]);
        __syncthreads();
        int src = 0, m = 1;
        for (int l = 1024; l >= 1; l >>= 1) {
            for (int w = tid; w < 1024; w += 256) {
                int k = w & (m - 1);
                int jm = w - k;
                float2 a = buf[src][k + jm];
                float2 bb = buf[src][k + jm + 1024];
                float2 tw = twl[jm];
                float dr = a.x - bb.x, di = a.y - bb.y;
                buf[src ^ 1][k + 2 * jm]     = make_float2(a.x + bb.x, a.y + bb.y);
                buf[src ^ 1][k + 2 * jm + m] = make_float2(dr * tw.x - di * tw.y,
                                                           dr * tw.y + di * tw.x);
            }
            __syncthreads();
            src ^= 1; m <<= 1;
        }
        for (int f = tid; f <= 1024; f += 256) {
            float2 p = buf[src][f];
            float2 q = buf[src][(2048 - f) & 2047];
            float ar = 0.5f * (p.x + q.x), ai = 0.5f * (p.y - q.y);
            float dr = p.x - q.x, di = p.y + q.y;
            float gr = 0.5f * di, gi = -0.5f * dr;
            Sacc[f].x += ar * gr + ai * gi;
            Sacc[f].y += ai * gr - ar * gi;
        }
    }
    __syncthreads();
    float* Sg = S + (size_t)b * NF * 2;
    for (int f = tid; f < NF; f += 256) {
        atomicAdd(&Sg[2 * f], Sacc[f].x);
        atomicAdd(&Sg[2 * f + 1], Sacc[f].y);
    }
}

// ---------------------------------------------------------------------------
// Per batch: inverse FFT of Hermitian spectrum -> mean_corr, top-4, softmax.
__global__ __launch_bounds__(256) void k_topk(const float* __restrict__ S,
                                              float* __restrict__ wts,
                                              int* __restrict__ idxs) {
    __shared__ float2 buf[2][2048];
    __shared__ float2 twl[1024];
    __shared__ float cv[2048];
    __shared__ float rv[256];
    __shared__ int ri[256];
    __shared__ float topv[TOPK];
    __shared__ int topi[TOPK];
    int tid = threadIdx.x;
    int b = blockIdx.x;
    const float* Sg = S + (size_t)b * NF * 2;
    for (int j = tid; j < 1024; j += 256) {
        float sn, cs;
        sincosf(6.283185307179586f * (float)j / 2048.0f, &sn, &cs);
        twl[j] = make_float2(cs, sn);
    }
    for (int f = tid; f < 2048; f += 256) {
        float re, im;
        if (f <= 1024) { re = Sg[2 * f]; im = Sg[2 * f + 1]; }
        else { re = Sg[2 * (2048 - f)]; im = -Sg[2 * (2048 - f) + 1]; }
        buf[0][f] = make_float2(re, im);
    }
    __syncthreads();
    int src = 0, m = 1;
    for (int l = 1024; l >= 1; l >>= 1) {
        for (int w = tid; w < 1024; w += 256) {
            int k = w & (m - 1);
            int jm = w - k;
            float2 a = buf[src][k + jm];
            float2 bb = buf[src][k + jm + 1024];
            float2 tw = twl[jm];
            float dr = a.x - bb.x, di = a.y - bb.y;
            buf[src ^ 1][k + 2 * jm]     = make_float2(a.x + bb.x, a.y + bb.y);
            buf[src ^ 1][k + 2 * jm + m] = make_float2(dr * tw.x - di * tw.y,
                                                       dr * tw.y + di * tw.x);
        }
        __syncthreads();
        src ^= 1; m <<= 1;
    }
    const float scale = 1.0f / ((float)LL * (float)DD);
    for (int f = tid; f < 2048; f += 256) cv[f] = buf[src][f].x * scale;
    __syncthreads();
    for (int r = 0; r < TOPK; r++) {
        float best = -3.0e38f;
        int bi = 0x7fffffff;
        for (int f = tid; f < 2048; f += 256) {
            bool taken = false;
            for (int q = 0; q < r; q++) taken |= (topi[q] == f);
            float v = cv[f];
            if (!taken && (v > best || (v == best && f < bi))) { best = v; bi = f; }
        }
        rv[tid] = best; ri[tid] = bi;
        __syncthreads();
        for (int s = 128; s > 0; s >>= 1) {
            if (tid < s) {
                float v2 = rv[tid + s]; int i2 = ri[tid + s];
                if (v2 > rv[tid] || (v2 == rv[tid] && i2 < ri[tid])) { rv[tid] = v2; ri[tid] = i2; }
            }
            __syncthreads();
        }
        if (tid == 0) { topv[r] = rv[0]; topi[r] = ri[0]; }
        __syncthreads();
    }
    if (tid == 0) {
        float mx = topv[0];
        float e[TOPK], sum = 0.f;
        for (int k = 0; k < TOPK; k++) { e[k] = expf(topv[k] - mx); sum += e[k]; }
        for (int k = 0; k < TOPK; k++) {
            wts[b * TOPK + k] = e[k] / sum;
            idxs[b * TOPK + k] = topi[k];
        }
    }
}

// ---------------------------------------------------------------------------
// out[b,l,:] = sum_k w_k * V[b,(l-idx_k)&2047,:]
__global__ __launch_bounds__(128) void k_agg(const float* __restrict__ V,
                                             const float* __restrict__ wts,
                                             const int* __restrict__ idxs,
                                             float* __restrict__ out) {
    int l = blockIdx.x, b = blockIdx.y;
    int t = threadIdx.x;
    const float4* Vb = (const float4*)(V + (size_t)b * LL * DD);
    float4 acc = make_float4(0.f, 0.f, 0.f, 0.f);
#pragma unroll
    for (int k = 0; k < TOPK; k++) {
        float w = wts[b * TOPK + k];
        int r = (l - idxs[b * TOPK + k]) & (LL - 1);
        float4 v = Vb[(size_t)r * 128 + t];
        acc.x += w * v.x; acc.y += w * v.y; acc.z += w * v.z; acc.w += w * v.w;
    }
    ((float4*)out)[((size_t)b * LL + l) * 128 + t] = acc;
}

// ---------------------------------------------------------------------------
extern "C" void kernel_launch(void* const* d_in, const int* in_sizes, int n_in,
                              void* d_out, int out_size, void* d_ws, size_t ws_size,
                              hipStream_t stream) {
    const float* x  = (const float*)d_in[0];
    const float* Wq = (const float*)d_in[1];
    const float* Wk = (const float*)d_in[3];
    const float* Wv = (const float*)d_in[5];
    const float* bv = (const float*)d_in[6];
    // bq, bk provably cancel (tau-independent shift; top-k & softmax shift-invariant)
    (void)in_sizes; (void)n_in; (void)out_size; (void)ws_size;

    float* ws  = (float*)d_ws;
    u16*   XB  = (u16*)(ws + OFF_XB);
    u16*   XTB = (u16*)(ws + OFF_XTB);
    float* GT  = ws + OFF_GT;
    float* V   = ws + OFF_V;
    u16*   BM  = (u16*)(ws + OFF_BBM);
    float* S   = ws + OFF_S;
    float* wts = ws + OFF_W;
    int*   idx = (int*)(ws + OFF_I);
    float* out = (float*)d_out;

    k_transpose<<<dim3(DD / 32, LL / 32, BB), 256, 0, stream>>>(x, XB, XTB);
    k_gemm1<<<dim3(DD / 64, DD / 64), 256, 0, stream>>>(Wq, Wk, BM);
    k_castwv<<<1024, 256, 0, stream>>>(Wv, BM);
    k_gemm2<<<dim3((BB * LL) / 128, (2 * DD) / 128), 256, 0, stream>>>(XB, BM, bv, GT, V);
    k_zero<<<32, 256, 0, stream>>>(S);
    k_fft<<<dim3(DD / 16, BB), 256, 0, stream>>>(XTB, GT, S);
    k_topk<<<BB, 256, 0, stream>>>(S, wts, idx);
    k_agg<<<dim3(LL, BB), 128, 0, stream>>>(V, wts, idx, out);
}

// Round 3
// 347.068 us; speedup vs baseline: 2.2708x; 1.1536x over previous
//
#include <hip/hip_runtime.h>
#include <math.h>

typedef unsigned short u16;
typedef unsigned int   u32;
typedef __attribute__((ext_vector_type(8))) __bf16 bf16x8;
typedef __attribute__((ext_vector_type(4))) float  f32x4;

#define BB 16
#define LL 2048
#define DD 512
#define NF 1025
#define TOPK 4

// ws layout (float-unit offsets), total ~169 MB
static const size_t OFF_XB  = 0;                         // bf16 x row-major [B*L][D]
static const size_t OFF_XTB = OFF_XB  + 8388608;         // bf16 x transposed [B][D][L]
static const size_t OFF_GT  = OFF_XTB + 8388608;         // f32 G transposed [B][D][L]
static const size_t OFF_XC  = OFF_GT  + 16777216;        // bf16 combined x [B*L][D]
static const size_t OFF_BBM = OFF_XC  + 8388608;         // bf16 Bmat [1024][512]: 0..511=M, 512..1023=Wv
static const size_t OFF_S   = OFF_BBM + 262144;          // spectra [B][NF][2]
static const size_t OFF_W   = OFF_S   + (size_t)BB * NF * 2;
static const size_t OFF_I   = OFF_W   + BB * TOPK;

__device__ __forceinline__ u16 f2bf(float f) {
    u32 u = __float_as_uint(f);
    return (u16)((u + 0x7fffu + ((u >> 16) & 1u)) >> 16);
}
__device__ __forceinline__ float bf2f(u16 h) {
    return __uint_as_float(((u32)h) << 16);
}
__device__ __forceinline__ void gload16(const void* g, void* l) {
    __builtin_amdgcn_global_load_lds((const __attribute__((address_space(1))) void*)g,
                                     (__attribute__((address_space(3))) void*)l, 16, 0, 0);
}
__device__ __forceinline__ float2 cmul(float2 u, float2 v) {
    return make_float2(u.x * v.x - u.y * v.y, u.x * v.y + u.y * v.x);
}
__device__ __forceinline__ float2 cadd(float2 u, float2 v) { return make_float2(u.x + v.x, u.y + v.y); }
__device__ __forceinline__ float2 csub(float2 u, float2 v) { return make_float2(u.x - v.x, u.y - v.y); }

// ---------------------------------------------------------------------------
// Radix-4 Stockham stage = fused radix-2 stages (M, 2M). 512 butterflies.
// Reads src[w+{0,512,1024,1536}] (lane-consecutive, conflict-free).
template<int M, int SGN>
__device__ __forceinline__ void radix4(const float2* __restrict__ src,
                                       float2* __restrict__ dst,
                                       const float2* __restrict__ twl, int tid) {
#pragma unroll
    for (int r = 0; r < 2; r++) {
        int w = tid + 256 * r;
        int k = w & (M - 1);
        int jm = w - k;                       // j*M
        float2 a = src[w], b = src[w + 512], c = src[w + 1024], d = src[w + 1536];
        float2 t0 = cadd(a, c), t1 = csub(a, c), t2 = cadd(b, d), bd = csub(b, d);
        float2 t3 = (SGN > 0) ? make_float2(bd.y, -bd.x)    // -i*(b-d), forward
                              : make_float2(-bd.y, bd.x);   // +i*(b-d), inverse
        float2 T1 = twl[jm];
        float2 T2 = twl[2 * jm];
        float2 T3 = cmul(T1, T2);
        int o = 4 * jm + k;
        dst[o]         = cadd(t0, t2);
        dst[o + M]     = cmul(cadd(t1, t3), T1);
        dst[o + 2 * M] = cmul(csub(t0, t2), T2);
        dst[o + 3 * M] = cmul(csub(t1, t3), T3);
    }
}

// Full 2048-pt complex FFT over LDS. Data starts AND ends in A. twl: 1024
// entries e^{SGN * -2pi i j/2048}. Caller barriers before (A loaded) / uses A after.
template<int SGN>
__device__ __forceinline__ void fft2048(float2* __restrict__ A, float2* __restrict__ Bf,
                                        const float2* __restrict__ twl, int tid) {
    // radix-2 stage m=1: A -> Bf
#pragma unroll
    for (int r = 0; r < 4; r++) {
        int j = tid + 256 * r;
        float2 a = A[j], b = A[j + 1024];
        Bf[2 * j]     = cadd(a, b);
        Bf[2 * j + 1] = cmul(csub(a, b), twl[j]);
    }
    __syncthreads();
    radix4<2,   SGN>(Bf, A, twl, tid); __syncthreads();
    radix4<8,   SGN>(A, Bf, twl, tid); __syncthreads();
    radix4<32,  SGN>(Bf, A, twl, tid); __syncthreads();
    radix4<128, SGN>(A, Bf, twl, tid); __syncthreads();
    radix4<512, SGN>(Bf, A, twl, tid); __syncthreads();
}

// ---------------------------------------------------------------------------
// x fp32 [B][L][D] -> XB bf16 row-major + XTB bf16 transposed [B][D][L]
__global__ __launch_bounds__(256) void k_transpose(const float* __restrict__ in,
                                                   u16* __restrict__ xb,
                                                   u16* __restrict__ xtb) {
    __shared__ u16 tile[32][33];
    int tx = threadIdx.x & 31, ty = threadIdx.x >> 5;
    int d0 = blockIdx.x * 32, t0 = blockIdx.y * 32, b = blockIdx.z;
    const float* ip = in + (size_t)b * LL * DD;
    u16* xbp = xb + (size_t)b * LL * DD;
    u16* xtp = xtb + (size_t)b * DD * LL;
#pragma unroll
    for (int i = 0; i < 4; i++) {
        float v = ip[(size_t)(t0 + ty + 8 * i) * DD + d0 + tx];
        u16 h = f2bf(v);
        xbp[(size_t)(t0 + ty + 8 * i) * DD + d0 + tx] = h;
        tile[ty + 8 * i][tx] = h;
    }
    __syncthreads();
#pragma unroll
    for (int i = 0; i < 4; i++)
        xtp[(size_t)(d0 + ty + 8 * i) * LL + t0 + tx] = tile[tx][ty + 8 * i];
}

// ---------------------------------------------------------------------------
// M = Wq^T * Wk (512^3) fp32 -> bf16 rows 0..511 of Bmat
__global__ __launch_bounds__(256) void k_gemm1(const float* __restrict__ Wq,
                                               const float* __restrict__ Wk,
                                               u16* __restrict__ Bm) {
    __shared__ float As[16][68];
    __shared__ float Bs[16][68];
    int t = threadIdx.x;
    int tx = t & 15, ty = t >> 4;
    int m0 = blockIdx.x * 64, n0 = blockIdx.y * 64;
    float acc[4][4] = {};
    for (int k0 = 0; k0 < DD; k0 += 16) {
#pragma unroll
        for (int r = 0; r < 4; r++) {
            As[ty][tx + 16 * r] = Wq[(size_t)(k0 + ty) * DD + m0 + tx + 16 * r];
            Bs[ty][tx + 16 * r] = Wk[(size_t)(k0 + ty) * DD + n0 + tx + 16 * r];
        }
        __syncthreads();
#pragma unroll
        for (int k = 0; k < 16; k++) {
            float4 a4 = *(const float4*)&As[k][ty * 4];
            float4 b4 = *(const float4*)&Bs[k][tx * 4];
            float a[4] = {a4.x, a4.y, a4.z, a4.w};
            float b[4] = {b4.x, b4.y, b4.z, b4.w};
#pragma unroll
            for (int i = 0; i < 4; i++)
#pragma unroll
                for (int j = 0; j < 4; j++) acc[i][j] += a[i] * b[j];
        }
        __syncthreads();
    }
#pragma unroll
    for (int i = 0; i < 4; i++) {
        uint2 o;
        o.x = (u32)f2bf(acc[i][0]) | ((u32)f2bf(acc[i][1]) << 16);
        o.y = (u32)f2bf(acc[i][2]) | ((u32)f2bf(acc[i][3]) << 16);
        *(uint2*)&Bm[(size_t)(m0 + ty * 4 + i) * DD + n0 + tx * 4] = o;
    }
}

__global__ __launch_bounds__(256) void k_castwv(const float* __restrict__ Wv,
                                                u16* __restrict__ Bm) {
    int i = blockIdx.x * 256 + threadIdx.x;
    Bm[DD * DD + i] = f2bf(Wv[i]);
}

// ---------------------------------------------------------------------------
// G = XB * M^T (bf16 MFMA), written transposed GT[b][d][t] fp32.
__global__ __launch_bounds__(256, 2) void k_gemm2(const u16* __restrict__ Ab,
                                                  const u16* __restrict__ Bm,
                                                  float* __restrict__ GT) {
    __shared__ u16 smem[16384];
    u16* As = smem;
    u16* Bs = smem + 8192;
    int t = threadIdx.x;
    int wave = t >> 6, lane = t & 63;
    int l15 = lane & 15, l4 = lane >> 4;
    int qr = wave & 1, qc = wave >> 1;
    int m0 = blockIdx.x * 128, n0 = blockIdx.y * 128;

    f32x4 acc[4][4];
#pragma unroll
    for (int i = 0; i < 4; i++)
#pragma unroll
        for (int j = 0; j < 4; j++) acc[i][j] = (f32x4){0.f, 0.f, 0.f, 0.f};

    const u16* Ag = Ab + (size_t)m0 * DD;
    const u16* Bg = Bm + (size_t)n0 * DD;
    int a_base = (qr * 64 + l15) * 64 + l4 * 8;
    int b_base = (qc * 64 + l15) * 64 + l4 * 8;

    for (int k0 = 0; k0 < DD; k0 += 64) {
#pragma unroll
        for (int n = 0; n < 4; n++) {
            int c = wave * 256 + n * 64 + lane;
            int row = c >> 3, col = (c & 7) * 8;
            gload16(Ag + (size_t)row * DD + k0 + col, (char*)As + (size_t)(wave * 256 + n * 64) * 16);
            gload16(Bg + (size_t)row * DD + k0 + col, (char*)Bs + (size_t)(wave * 256 + n * 64) * 16);
        }
        __syncthreads();
#pragma unroll
        for (int kk = 0; kk < 64; kk += 32) {
            bf16x8 af[4], bq[4];
#pragma unroll
            for (int i = 0; i < 4; i++) af[i] = *(const bf16x8*)(As + a_base + i * 1024 + kk);
#pragma unroll
            for (int j = 0; j < 4; j++) bq[j] = *(const bf16x8*)(Bs + b_base + j * 1024 + kk);
#pragma unroll
            for (int i = 0; i < 4; i++)
#pragma unroll
                for (int j = 0; j < 4; j++)
                    acc[i][j] = __builtin_amdgcn_mfma_f32_16x16x32_bf16(af[i], bq[j], acc[i][j], 0, 0, 0);
        }
        __syncthreads();
    }

    // Epilogue: write transposed GT[b][n][t] via swizzled LDS staging
    float4* tb4 = (float4*)smem;
    int bidx = m0 >> 11;
    int tbase = m0 & 2047;
#pragma unroll
    for (int p = 0; p < 2; p++) {
        __syncthreads();
        if (qc == p) {
#pragma unroll
            for (int j = 0; j < 4; j++) {
                int nloc = j * 16 + l15;
#pragma unroll
                for (int i = 0; i < 4; i++) {
                    int tq = qr * 16 + i * 4 + l4;
                    tb4[nloc * 32 + (tq ^ (nloc & 31))] = *(float4*)&acc[i][j];
                }
            }
        }
        __syncthreads();
#pragma unroll
        for (int u = 0; u < 8; u++) {
            int idx4 = u * 256 + t;
            int nloc = idx4 >> 5, c4 = idx4 & 31;
            float4 v = tb4[nloc * 32 + (c4 ^ (nloc & 31))];
            *(float4*)&GT[((size_t)bidx * DD + n0 + p * 64 + nloc) * LL + tbase + c4 * 4] = v;
        }
    }
}

// ---------------------------------------------------------------------------
// out = XC * Wv^T + bv (bf16 MFMA), row-major fp32 into d_out.
__global__ __launch_bounds__(256, 2) void k_gemm3(const u16* __restrict__ Ab,
                                                  const u16* __restrict__ Bm,
                                                  const float* __restrict__ bv,
                                                  float* __restrict__ out) {
    __shared__ u16 smem[16384];
    u16* As = smem;
    u16* Bs = smem + 8192;
    int t = threadIdx.x;
    int wave = t >> 6, lane = t & 63;
    int l15 = lane & 15, l4 = lane >> 4;
    int qr = wave & 1, qc = wave >> 1;
    int m0 = blockIdx.x * 128, n0 = blockIdx.y * 128;

    f32x4 acc[4][4];
#pragma unroll
    for (int i = 0; i < 4; i++)
#pragma unroll
        for (int j = 0; j < 4; j++) acc[i][j] = (f32x4){0.f, 0.f, 0.f, 0.f};

    const u16* Ag = Ab + (size_t)m0 * DD;
    const u16* Bg = Bm + (size_t)DD * DD + (size_t)n0 * DD;   // Wv rows
    int a_base = (qr * 64 + l15) * 64 + l4 * 8;
    int b_base = (qc * 64 + l15) * 64 + l4 * 8;

    for (int k0 = 0; k0 < DD; k0 += 64) {
#pragma unroll
        for (int n = 0; n < 4; n++) {
            int c = wave * 256 + n * 64 + lane;
            int row = c >> 3, col = (c & 7) * 8;
            gload16(Ag + (size_t)row * DD + k0 + col, (char*)As + (size_t)(wave * 256 + n * 64) * 16);
            gload16(Bg + (size_t)row * DD + k0 + col, (char*)Bs + (size_t)(wave * 256 + n * 64) * 16);
        }
        __syncthreads();
#pragma unroll
        for (int kk = 0; kk < 64; kk += 32) {
            bf16x8 af[4], bq[4];
#pragma unroll
            for (int i = 0; i < 4; i++) af[i] = *(const bf16x8*)(As + a_base + i * 1024 + kk);
#pragma unroll
            for (int j = 0; j < 4; j++) bq[j] = *(const bf16x8*)(Bs + b_base + j * 1024 + kk);
#pragma unroll
            for (int i = 0; i < 4; i++)
#pragma unroll
                for (int j = 0; j < 4; j++)
                    acc[i][j] = __builtin_amdgcn_mfma_f32_16x16x32_bf16(af[i], bq[j], acc[i][j], 0, 0, 0);
        }
        __syncthreads();
    }

    // Epilogue: row-major + bias (swizzled LDS staging)
    float*  tb  = (float*)smem;
    float4* tb4 = (float4*)smem;
#pragma unroll
    for (int p = 0; p < 2; p++) {
        __syncthreads();
        if (qr == p) {
#pragma unroll
            for (int j = 0; j < 4; j++) {
                int nloc = qc * 64 + j * 16 + l15;
#pragma unroll
                for (int i = 0; i < 4; i++) {
#pragma unroll
                    for (int r = 0; r < 4; r++) {
                        int mloc = i * 16 + l4 * 4 + r;
                        int nc = ((nloc >> 2) ^ (mloc & 31)) << 2;
                        tb[mloc * 128 + nc + (nloc & 3)] = acc[i][j][r];
                    }
                }
            }
        }
        __syncthreads();
#pragma unroll
        for (int u = 0; u < 8; u++) {
            int idx4 = u * 256 + t;
            int mloc = idx4 >> 5, c4 = idx4 & 31;
            float4 v = tb4[mloc * 32 + (c4 ^ (mloc & 31))];
            float4 bias = *(const float4*)&bv[n0 + c4 * 4];
            v.x += bias.x; v.y += bias.y; v.z += bias.z; v.w += bias.w;
            *(float4*)&out[(size_t)(m0 + p * 64 + mloc) * DD + n0 + c4 * 4] = v;
        }
    }
}

// ---------------------------------------------------------------------------
__global__ void k_zero(float* __restrict__ S) {
    int i = blockIdx.x * 256 + threadIdx.x;
    int n = BB * NF * 2;
    for (; i < n; i += gridDim.x * 256) S[i] = 0.f;
}

// ---------------------------------------------------------------------------
// Per (b, 8-channel group): packed FFT of z = x_d + i*G_d (radix-4 Stockham),
// Hermitian split, accumulate S += Xf * conj(Gf). Grid 64x16 -> 3 blocks/CU.
__global__ __launch_bounds__(256) void k_fft(const u16* __restrict__ XTB,
                                             const float* __restrict__ GT,
                                             float* __restrict__ S) {
    __shared__ float2 A[2048];
    __shared__ float2 Bf[2048];
    __shared__ float2 twl[1024];
    __shared__ float2 Sacc[NF];
    int tid = threadIdx.x;
    int grp = blockIdx.x;    // 0..63
    int b = blockIdx.y;
    for (int j = tid; j < 1024; j += 256) {
        float sn, cs;
        sincosf(-6.283185307179586f * (float)j / 2048.0f, &sn, &cs);
        twl[j] = make_float2(cs, sn);
    }
    for (int f = tid; f < NF; f += 256) Sacc[f] = make_float2(0.f, 0.f);
    for (int c = 0; c < 8; c++) {
        int d = grp * 8 + c;
        const u16*   xp = XTB + ((size_t)b * DD + d) * LL;
        const float* gp = GT  + ((size_t)b * DD + d) * LL;
        __syncthreads();   // prev channel's reads of A done (also covers twl/Sacc init)
#pragma unroll
        for (int r = 0; r < 8; r++) {
            int i = tid + 256 * r;
            A[i] = make_float2(bf2f(xp[i]), gp[i]);
        }
        __syncthreads();
        fft2048<1>(A, Bf, twl, tid);       // result in A
        for (int f = tid; f <= 1024; f += 256) {
            float2 p = A[f];
            float2 q = A[(2048 - f) & 2047];
            float ar = 0.5f * (p.x + q.x), ai = 0.5f * (p.y - q.y);
            float dr = p.x - q.x, di = p.y + q.y;
            float gr = 0.5f * di, gi = -0.5f * dr;
            Sacc[f].x += ar * gr + ai * gi;
            Sacc[f].y += ai * gr - ar * gi;
        }
    }
    __syncthreads();
    float* Sg = S + (size_t)b * NF * 2;
    for (int f = tid; f < NF; f += 256) {
        atomicAdd(&Sg[2 * f], Sacc[f].x);
        atomicAdd(&Sg[2 * f + 1], Sacc[f].y);
    }
}

// ---------------------------------------------------------------------------
// Per batch: inverse FFT (radix-4) -> mean_corr, top-4, softmax.
__global__ __launch_bounds__(256) void k_topk(const float* __restrict__ S,
                                              float* __restrict__ wts,
                                              int* __restrict__ idxs) {
    __shared__ float2 A[2048];
    __shared__ float2 Bf[2048];
    __shared__ float2 twl[1024];
    __shared__ float cv[2048];
    __shared__ float rv[256];
    __shared__ int ri[256];
    __shared__ float topv[TOPK];
    __shared__ int topi[TOPK];
    int tid = threadIdx.x;
    int b = blockIdx.x;
    const float* Sg = S + (size_t)b * NF * 2;
    for (int j = tid; j < 1024; j += 256) {
        float sn, cs;
        sincosf(6.283185307179586f * (float)j / 2048.0f, &sn, &cs);   // inverse sign
        twl[j] = make_float2(cs, sn);
    }
    for (int f = tid; f < 2048; f += 256) {
        float re, im;
        if (f <= 1024) { re = Sg[2 * f]; im = Sg[2 * f + 1]; }
        else { re = Sg[2 * (2048 - f)]; im = -Sg[2 * (2048 - f) + 1]; }
        A[f] = make_float2(re, im);
    }
    __syncthreads();
    fft2048<-1>(A, Bf, twl, tid);   // result in A
    const float scale = 1.0f / ((float)LL * (float)DD);
    for (int f = tid; f < 2048; f += 256) cv[f] = A[f].x * scale;
    __syncthreads();
    for (int r = 0; r < TOPK; r++) {
        float best = -3.0e38f;
        int bi = 0x7fffffff;
        for (int f = tid; f < 2048; f += 256) {
            bool taken = false;
            for (int q = 0; q < r; q++) taken |= (topi[q] == f);
            float v = cv[f];
            if (!taken && (v > best || (v == best && f < bi))) { best = v; bi = f; }
        }
        rv[tid] = best; ri[tid] = bi;
        __syncthreads();
        for (int s = 128; s > 0; s >>= 1) {
            if (tid < s) {
                float v2 = rv[tid + s]; int i2 = ri[tid + s];
                if (v2 > rv[tid] || (v2 == rv[tid] && i2 < ri[tid])) { rv[tid] = v2; ri[tid] = i2; }
            }
            __syncthreads();
        }
        if (tid == 0) { topv[r] = rv[0]; topi[r] = ri[0]; }
        __syncthreads();
    }
    if (tid == 0) {
        float mx = topv[0];
        float e[TOPK], sum = 0.f;
        for (int k = 0; k < TOPK; k++) { e[k] = expf(topv[k] - mx); sum += e[k]; }
        for (int k = 0; k < TOPK; k++) {
            wts[b * TOPK + k] = e[k] / sum;
            idxs[b * TOPK + k] = topi[k];
        }
    }
}

// ---------------------------------------------------------------------------
// XC[b,l,:] = round_bf16( sum_k w_k * XB[b,(l-idx_k)&2047,:] )
__global__ __launch_bounds__(128) void k_combine(const u16* __restrict__ XB,
                                                 const float* __restrict__ wts,
                                                 const int* __restrict__ idxs,
                                                 u16* __restrict__ XC) {
    int l = blockIdx.x, b = blockIdx.y;
    int t = threadIdx.x;   // 128 threads x ushort4 = 512 u16
    const ushort4* Xb = (const ushort4*)(XB + (size_t)b * LL * DD);
    float4 acc = make_float4(0.f, 0.f, 0.f, 0.f);
#pragma unroll
    for (int k = 0; k < TOPK; k++) {
        float w = wts[b * TOPK + k];
        int r = (l - idxs[b * TOPK + k]) & (LL - 1);
        ushort4 v = Xb[(size_t)r * 128 + t];
        acc.x += w * bf2f(v.x); acc.y += w * bf2f(v.y);
        acc.z += w * bf2f(v.z); acc.w += w * bf2f(v.w);
    }
    ushort4 o;
    o.x = f2bf(acc.x); o.y = f2bf(acc.y); o.z = f2bf(acc.z); o.w = f2bf(acc.w);
    ((ushort4*)(XC + (size_t)b * LL * DD))[(size_t)l * 128 + t] = o;
}

// ---------------------------------------------------------------------------
extern "C" void kernel_launch(void* const* d_in, const int* in_sizes, int n_in,
                              void* d_out, int out_size, void* d_ws, size_t ws_size,
                              hipStream_t stream) {
    const float* x  = (const float*)d_in[0];
    const float* Wq = (const float*)d_in[1];
    const float* Wk = (const float*)d_in[3];
    const float* Wv = (const float*)d_in[5];
    const float* bv = (const float*)d_in[6];
    // bq, bk provably cancel (tau-independent shift; top-k & softmax shift-invariant)
    (void)in_sizes; (void)n_in; (void)out_size; (void)ws_size;

    float* ws  = (float*)d_ws;
    u16*   XB  = (u16*)(ws + OFF_XB);
    u16*   XTB = (u16*)(ws + OFF_XTB);
    float* GT  = ws + OFF_GT;
    u16*   XC  = (u16*)(ws + OFF_XC);
    u16*   BM  = (u16*)(ws + OFF_BBM);
    float* S   = ws + OFF_S;
    float* wts = ws + OFF_W;
    int*   idx = (int*)(ws + OFF_I);
    float* out = (float*)d_out;

    k_transpose<<<dim3(DD / 32, LL / 32, BB), 256, 0, stream>>>(x, XB, XTB);
    k_gemm1<<<dim3(DD / 64, DD / 64), 256, 0, stream>>>(Wq, Wk, BM);
    k_castwv<<<1024, 256, 0, stream>>>(Wv, BM);
    k_gemm2<<<dim3((BB * LL) / 128, DD / 128), 256, 0, stream>>>(XB, BM, GT);
    k_zero<<<32, 256, 0, stream>>>(S);
    k_fft<<<dim3(64, BB), 256, 0, stream>>>(XTB, GT, S);
    k_topk<<<BB, 256, 0, stream>>>(S, wts, idx);
    k_combine<<<dim3(LL, BB), 128, 0, stream>>>(XB, wts, idx, XC);
    k_gemm3<<<dim3((BB * LL) / 128, DD / 128), 256, 0, stream>>>(XC, BM, bv, out);
}

// Round 4
// 326.760 us; speedup vs baseline: 2.4119x; 1.0621x over previous
//
#include <hip/hip_runtime.h>
#include <math.h>

typedef unsigned short u16;
typedef unsigned int   u32;
typedef __attribute__((ext_vector_type(8))) __bf16 bf16x8;
typedef __attribute__((ext_vector_type(4))) float  f32x4;

#define BB 16
#define LL 2048
#define DD 512
#define NF 1025
#define TOPK 4

// ws layout (float-unit offsets), total ~136 MB
static const size_t OFF_XB  = 0;                         // bf16 x row-major [B*L][D]
static const size_t OFF_XTB = OFF_XB  + 8388608;         // bf16 x transposed [B][D][L]
static const size_t OFF_GTB = OFF_XTB + 8388608;         // bf16 G transposed [B][D][L]
static const size_t OFF_XC  = OFF_GTB + 8388608;         // bf16 combined x [B*L][D]
static const size_t OFF_BBM = OFF_XC  + 8388608;         // bf16 Bmat [1024][512]: 0..511=M, 512..1023=Wv
static const size_t OFF_S   = OFF_BBM + 262144;          // spectra [B][NF][2]
static const size_t OFF_W   = OFF_S   + (size_t)BB * NF * 2;
static const size_t OFF_I   = OFF_W   + BB * TOPK;

__device__ __forceinline__ u16 f2bf(float f) {
    u32 u = __float_as_uint(f);
    return (u16)((u + 0x7fffu + ((u >> 16) & 1u)) >> 16);
}
__device__ __forceinline__ float bf2f(u16 h) {
    return __uint_as_float(((u32)h) << 16);
}
__device__ __forceinline__ void gload16(const void* g, void* l) {
    __builtin_amdgcn_global_load_lds((const __attribute__((address_space(1))) void*)g,
                                     (__attribute__((address_space(3))) void*)l, 16, 0, 0);
}
__device__ __forceinline__ float2 cmul(float2 u, float2 v) {
    return make_float2(u.x * v.x - u.y * v.y, u.x * v.y + u.y * v.x);
}
__device__ __forceinline__ float2 cadd(float2 u, float2 v) { return make_float2(u.x + v.x, u.y + v.y); }
__device__ __forceinline__ float2 csub(float2 u, float2 v) { return make_float2(u.x - v.x, u.y - v.y); }

// ---------------------------------------------------------------------------
// Radix-4 Stockham stage (verified r3). T2=T1^2 computed (saves strided twl read).
template<int M, int SGN>
__device__ __forceinline__ void radix4(const float2* __restrict__ src,
                                       float2* __restrict__ dst,
                                       const float2* __restrict__ twl, int tid) {
#pragma unroll
    for (int r = 0; r < 2; r++) {
        int w = tid + 256 * r;
        int k = w & (M - 1);
        int jm = w - k;
        float2 a = src[w], b = src[w + 512], c = src[w + 1024], d = src[w + 1536];
        float2 t0 = cadd(a, c), t1 = csub(a, c), t2 = cadd(b, d), bd = csub(b, d);
        float2 t3 = (SGN > 0) ? make_float2(bd.y, -bd.x)
                              : make_float2(-bd.y, bd.x);
        float2 T1 = twl[jm];
        float2 T2 = cmul(T1, T1);
        float2 T3 = cmul(T1, T2);
        int o = 4 * jm + k;
        dst[o]         = cadd(t0, t2);
        dst[o + M]     = cmul(cadd(t1, t3), T1);
        dst[o + 2 * M] = cmul(csub(t1, t3), T3);
        dst[o + M]     = cmul(cadd(t1, t3), T1);
        dst[o + 2 * M] = cmul(csub(t0, t2), T2);
        dst[o + 3 * M] = cmul(csub(t1, t3), T3);
    }
}

// 5 radix-4 stages (input must hold the m=2 Stockham state, i.e. after the
// fused radix-2). b1 -> ... -> result in b2. Caller barriers before entry.
template<int SGN>
__device__ __forceinline__ void fft_r4_chain(float2* __restrict__ b1, float2* __restrict__ b2,
                                             const float2* __restrict__ twl, int tid) {
    radix4<2,   SGN>(b1, b2, twl, tid); __syncthreads();
    radix4<8,   SGN>(b2, b1, twl, tid); __syncthreads();
    radix4<32,  SGN>(b1, b2, twl, tid); __syncthreads();
    radix4<128, SGN>(b2, b1, twl, tid); __syncthreads();
    radix4<512, SGN>(b1, b2, twl, tid); __syncthreads();
}

// ---------------------------------------------------------------------------
// Merged prologue: [transpose+cast x] + [gemm1 M=Wq^T*Wk] + [cast Wv, zero S]
__global__ __launch_bounds__(256) void k_pre(const float* __restrict__ x,
                                             const float* __restrict__ Wq,
                                             const float* __restrict__ Wk,
                                             const float* __restrict__ Wv,
                                             u16* __restrict__ xb,
                                             u16* __restrict__ xtb,
                                             u16* __restrict__ Bm,
                                             float* __restrict__ S) {
    __shared__ char sh[8704];
    int bid = blockIdx.x;
    int tid = threadIdx.x;
    if (bid < 16384) {
        // ---- transpose branch: x fp32 -> XB bf16 row-major + XTB bf16 transposed
        u16 (*tile)[33] = (u16(*)[33])sh;
        int bx = bid & 15, by = (bid >> 4) & 63, bz = bid >> 10;
        int tx = tid & 31, ty = tid >> 5;
        int d0 = bx * 32, t0 = by * 32;
        const float* ip = x + (size_t)bz * LL * DD;
        u16* xbp = xb + (size_t)bz * LL * DD;
        u16* xtp = xtb + (size_t)bz * DD * LL;
#pragma unroll
        for (int i = 0; i < 4; i++) {
            float v = ip[(size_t)(t0 + ty + 8 * i) * DD + d0 + tx];
            u16 h = f2bf(v);
            xbp[(size_t)(t0 + ty + 8 * i) * DD + d0 + tx] = h;
            tile[ty + 8 * i][tx] = h;
        }
        __syncthreads();
#pragma unroll
        for (int i = 0; i < 4; i++)
            xtp[(size_t)(d0 + ty + 8 * i) * LL + t0 + tx] = tile[tx][ty + 8 * i];
    } else if (bid < 16448) {
        // ---- gemm1 branch: M = Wq^T * Wk -> bf16 rows 0..511 of Bmat
        int g = bid - 16384;
        float (*As)[68] = (float(*)[68])sh;
        float (*Bs)[68] = (float(*)[68])(sh + 4352);
        int tx = tid & 15, ty = tid >> 4;
        int m0 = (g & 7) * 64, n0 = (g >> 3) * 64;
        float acc[4][4] = {};
        for (int k0 = 0; k0 < DD; k0 += 16) {
#pragma unroll
            for (int r = 0; r < 4; r++) {
                As[ty][tx + 16 * r] = Wq[(size_t)(k0 + ty) * DD + m0 + tx + 16 * r];
                Bs[ty][tx + 16 * r] = Wk[(size_t)(k0 + ty) * DD + n0 + tx + 16 * r];
            }
            __syncthreads();
#pragma unroll
            for (int k = 0; k < 16; k++) {
                float4 a4 = *(const float4*)&As[k][ty * 4];
                float4 b4 = *(const float4*)&Bs[k][tx * 4];
                float a[4] = {a4.x, a4.y, a4.z, a4.w};
                float b[4] = {b4.x, b4.y, b4.z, b4.w};
#pragma unroll
                for (int i = 0; i < 4; i++)
#pragma unroll
                    for (int j = 0; j < 4; j++) acc[i][j] += a[i] * b[j];
            }
            __syncthreads();
        }
#pragma unroll
        for (int i = 0; i < 4; i++) {
            uint2 o;
            o.x = (u32)f2bf(acc[i][0]) | ((u32)f2bf(acc[i][1]) << 16);
            o.y = (u32)f2bf(acc[i][2]) | ((u32)f2bf(acc[i][3]) << 16);
            *(uint2*)&Bm[(size_t)(m0 + ty * 4 + i) * DD + n0 + tx * 4] = o;
        }
    } else {
        // ---- misc branch: cast Wv (rows 512..1023 of Bmat), zero S
        int g = bid - 16448;                 // 0..255
        int i4 = g * 256 + tid;              // float4 index over 512*512
        float4 w = ((const float4*)Wv)[i4];
        ushort4 o;
        o.x = f2bf(w.x); o.y = f2bf(w.y); o.z = f2bf(w.z); o.w = f2bf(w.w);
        ((ushort4*)(Bm + DD * DD))[i4] = o;
        if (i4 < 8200)                       // 32800 floats = 8200 float4
            ((float4*)S)[i4] = make_float4(0.f, 0.f, 0.f, 0.f);
    }
}

// ---------------------------------------------------------------------------
// G = XB * M^T (bf16 MFMA), written transposed bf16 GTB[b][d][t].
__global__ __launch_bounds__(256, 2) void k_gemm2(const u16* __restrict__ Ab,
                                                  const u16* __restrict__ Bm,
                                                  u16* __restrict__ GTB) {
    __shared__ u16 smem[16384];
    u16* As = smem;
    u16* Bs = smem + 8192;
    int t = threadIdx.x;
    int wave = t >> 6, lane = t & 63;
    int l15 = lane & 15, l4 = lane >> 4;
    int qr = wave & 1, qc = wave >> 1;
    int m0 = blockIdx.x * 128, n0 = blockIdx.y * 128;

    f32x4 acc[4][4];
#pragma unroll
    for (int i = 0; i < 4; i++)
#pragma unroll
        for (int j = 0; j < 4; j++) acc[i][j] = (f32x4){0.f, 0.f, 0.f, 0.f};

    const u16* Ag = Ab + (size_t)m0 * DD;
    const u16* Bg = Bm + (size_t)n0 * DD;
    int a_base = (qr * 64 + l15) * 64 + l4 * 8;
    int b_base = (qc * 64 + l15) * 64 + l4 * 8;

    for (int k0 = 0; k0 < DD; k0 += 64) {
#pragma unroll
        for (int n = 0; n < 4; n++) {
            int c = wave * 256 + n * 64 + lane;
            int row = c >> 3, col = (c & 7) * 8;
            gload16(Ag + (size_t)row * DD + k0 + col, (char*)As + (size_t)(wave * 256 + n * 64) * 16);
            gload16(Bg + (size_t)row * DD + k0 + col, (char*)Bs + (size_t)(wave * 256 + n * 64) * 16);
        }
        __syncthreads();
#pragma unroll
        for (int kk = 0; kk < 64; kk += 32) {
            bf16x8 af[4], bq[4];
#pragma unroll
            for (int i = 0; i < 4; i++) af[i] = *(const bf16x8*)(As + a_base + i * 1024 + kk);
#pragma unroll
            for (int j = 0; j < 4; j++) bq[j] = *(const bf16x8*)(Bs + b_base + j * 1024 + kk);
#pragma unroll
            for (int i = 0; i < 4; i++)
#pragma unroll
                for (int j = 0; j < 4; j++)
                    acc[i][j] = __builtin_amdgcn_mfma_f32_16x16x32_bf16(af[i], bq[j], acc[i][j], 0, 0, 0);
        }
        __syncthreads();
    }

    // Epilogue: transposed bf16 write via swizzled LDS staging
    float4* tb4 = (float4*)smem;
    int bidx = m0 >> 11;
    int tbase = m0 & 2047;
#pragma unroll
    for (int p = 0; p < 2; p++) {
        __syncthreads();
        if (qc == p) {
#pragma unroll
            for (int j = 0; j < 4; j++) {
                int nloc = j * 16 + l15;
#pragma unroll
                for (int i = 0; i < 4; i++) {
                    int tq = qr * 16 + i * 4 + l4;
                    tb4[nloc * 32 + (tq ^ (nloc & 31))] = *(float4*)&acc[i][j];
                }
            }
        }
        __syncthreads();
#pragma unroll
        for (int u = 0; u < 8; u++) {
            int idx4 = u * 256 + t;
            int nloc = idx4 >> 5, c4 = idx4 & 31;
            float4 v = tb4[nloc * 32 + (c4 ^ (nloc & 31))];
            uint2 o;
            o.x = (u32)f2bf(v.x) | ((u32)f2bf(v.y) << 16);
            o.y = (u32)f2bf(v.z) | ((u32)f2bf(v.w) << 16);
            *(uint2*)&GTB[((size_t)bidx * DD + n0 + p * 64 + nloc) * LL + tbase + c4 * 4] = o;
        }
    }
}

// ---------------------------------------------------------------------------
// out = XC * Wv^T + bv (bf16 MFMA), row-major fp32 into d_out.
__global__ __launch_bounds__(256, 2) void k_gemm3(const u16* __restrict__ Ab,
                                                  const u16* __restrict__ Bm,
                                                  const float* __restrict__ bv,
                                                  float* __restrict__ out) {
    __shared__ u16 smem[16384];
    u16* As = smem;
    u16* Bs = smem + 8192;
    int t = threadIdx.x;
    int wave = t >> 6, lane = t & 63;
    int l15 = lane & 15, l4 = lane >> 4;
    int qr = wave & 1, qc = wave >> 1;
    int m0 = blockIdx.x * 128, n0 = blockIdx.y * 128;

    f32x4 acc[4][4];
#pragma unroll
    for (int i = 0; i < 4; i++)
#pragma unroll
        for (int j = 0; j < 4; j++) acc[i][j] = (f32x4){0.f, 0.f, 0.f, 0.f};

    const u16* Ag = Ab + (size_t)m0 * DD;
    const u16* Bg = Bm + (size_t)DD * DD + (size_t)n0 * DD;
    int a_base = (qr * 64 + l15) * 64 + l4 * 8;
    int b_base = (qc * 64 + l15) * 64 + l4 * 8;

    for (int k0 = 0; k0 < DD; k0 += 64) {
#pragma unroll
        for (int n = 0; n < 4; n++) {
            int c = wave * 256 + n * 64 + lane;
            int row = c >> 3, col = (c & 7) * 8;
            gload16(Ag + (size_t)row * DD + k0 + col, (char*)As + (size_t)(wave * 256 + n * 64) * 16);
            gload16(Bg + (size_t)row * DD + k0 + col, (char*)Bs + (size_t)(wave * 256 + n * 64) * 16);
        }
        __syncthreads();
#pragma unroll
        for (int kk = 0; kk < 64; kk += 32) {
            bf16x8 af[4], bq[4];
#pragma unroll
            for (int i = 0; i < 4; i++) af[i] = *(const bf16x8*)(As + a_base + i * 1024 + kk);
#pragma unroll
            for (int j = 0; j < 4; j++) bq[j] = *(const bf16x8*)(Bs + b_base + j * 1024 + kk);
#pragma unroll
            for (int i = 0; i < 4; i++)
#pragma unroll
                for (int j = 0; j < 4; j++)
                    acc[i][j] = __builtin_amdgcn_mfma_f32_16x16x32_bf16(af[i], bq[j], acc[i][j], 0, 0, 0);
        }
        __syncthreads();
    }

    float*  tb  = (float*)smem;
    float4* tb4 = (float4*)smem;
#pragma unroll
    for (int p = 0; p < 2; p++) {
        __syncthreads();
        if (qr == p) {
#pragma unroll
            for (int j = 0; j < 4; j++) {
                int nloc = qc * 64 + j * 16 + l15;
#pragma unroll
                for (int i = 0; i < 4; i++) {
#pragma unroll
                    for (int r = 0; r < 4; r++) {
                        int mloc = i * 16 + l4 * 4 + r;
                        int nc = ((nloc >> 2) ^ (mloc & 31)) << 2;
                        tb[mloc * 128 + nc + (nloc & 3)] = acc[i][j][r];
                    }
                }
            }
        }
        __syncthreads();
#pragma unroll
        for (int u = 0; u < 8; u++) {
            int idx4 = u * 256 + t;
            int mloc = idx4 >> 5, c4 = idx4 & 31;
            float4 v = tb4[mloc * 32 + (c4 ^ (mloc & 31))];
            float4 bias = *(const float4*)&bv[n0 + c4 * 4];
            v.x += bias.x; v.y += bias.y; v.z += bias.z; v.w += bias.w;
            *(float4*)&out[(size_t)(m0 + p * 64 + mloc) * DD + n0 + c4 * 4] = v;
        }
    }
}

// ---------------------------------------------------------------------------
// Per (b, 8-channel group): packed FFT of z = x_d + i*G_d. Radix-2 fused into
// the load phase; 5 radix-4 stages; Hermitian split accumulated in REGISTERS.
// LDS = exactly 40 KiB -> 4 blocks/CU; grid 1024 -> full residency.
__global__ __launch_bounds__(256) void k_fft(const u16* __restrict__ XTB,
                                             const u16* __restrict__ GTB,
                                             float* __restrict__ S) {
    __shared__ float2 lds[5120];      // buf1[2048] | buf2[2048] | twl[1024] = 40960 B
    float2* b1  = lds;
    float2* b2  = lds + 2048;
    float2* twl = lds + 4096;
    int tid = threadIdx.x;
    int grp = blockIdx.x;    // 0..63
    int b = blockIdx.y;
    for (int j = tid; j < 1024; j += 256) {
        float sn, cs;
        sincosf(-6.283185307179586f * (float)j / 2048.0f, &sn, &cs);
        twl[j] = make_float2(cs, sn);
    }
    __syncthreads();
    float2 sr[4];
#pragma unroll
    for (int r = 0; r < 4; r++) sr[r] = make_float2(0.f, 0.f);
    float2 s1024 = make_float2(0.f, 0.f);

    for (int c = 0; c < 8; c++) {
        int d = grp * 8 + c;
        const u16* xp = XTB + ((size_t)b * DD + d) * LL;
        const u16* gp = GTB + ((size_t)b * DD + d) * LL;
        // fused load + radix-2 (j0, j0+1 paired with +1024) -> b1 (m=2 state)
#pragma unroll
        for (int h = 0; h < 2; h++) {
            int j0 = 2 * tid + 512 * h;
            u32 xl = *(const u32*)&xp[j0];
            u32 xh = *(const u32*)&xp[j0 + 1024];
            u32 gl = *(const u32*)&gp[j0];
            u32 gh = *(const u32*)&gp[j0 + 1024];
            float2 a0 = make_float2(bf2f((u16)xl), bf2f((u16)gl));
            float2 a1 = make_float2(bf2f((u16)(xl >> 16)), bf2f((u16)(gl >> 16)));
            float2 c0 = make_float2(bf2f((u16)xh), bf2f((u16)gh));
            float2 c1 = make_float2(bf2f((u16)(xh >> 16)), bf2f((u16)(gh >> 16)));
            b1[2 * j0]     = cadd(a0, c0);
            b1[2 * j0 + 1] = cmul(csub(a0, c0), twl[j0]);
            b1[2 * j0 + 2] = cadd(a1, c1);
            b1[2 * j0 + 3] = cmul(csub(a1, c1), twl[j0 + 1]);
        }
        __syncthreads();
        fft_r4_chain<1>(b1, b2, twl, tid);      // result in b2
        // Hermitian split + accumulate S += Xf * conj(Gf)  (registers)
#pragma unroll
        for (int r = 0; r < 4; r++) {
            int f = tid + 256 * r;
            float2 p = b2[f];
            float2 q = b2[(2048 - f) & 2047];
            float ar = 0.5f * (p.x + q.x), ai = 0.5f * (p.y - q.y);
            float dr = p.x - q.x, di = p.y + q.y;
            float gr = 0.5f * di, gi = -0.5f * dr;
            sr[r].x += ar * gr + ai * gi;
            sr[r].y += ai * gr - ar * gi;
        }
        if (tid == 0) {
            float2 p = b2[1024];
            // f=1024: q=p -> ar=p.x, ai=0, gr=p.y, gi=0
            s1024.x += p.x * p.y;
        }
        // next load writes b1 (safe: last b1 reader barriered inside chain);
        // accumulate reads of b2 complete before next chain's first barrier.
    }
    float* Sg = S + (size_t)b * NF * 2;
#pragma unroll
    for (int r = 0; r < 4; r++) {
        int f = tid + 256 * r;
        atomicAdd(&Sg[2 * f], sr[r].x);
        atomicAdd(&Sg[2 * f + 1], sr[r].y);
    }
    if (tid == 0) {
        atomicAdd(&Sg[2048], s1024.x);
        atomicAdd(&Sg[2049], s1024.y);
    }
}

// ---------------------------------------------------------------------------
// Per batch: inverse FFT (fused-r2 load of Hermitian-extended spectrum) ->
// mean_corr, top-4, softmax.
__global__ __launch_bounds__(256) void k_topk(const float* __restrict__ S,
                                              float* __restrict__ wts,
                                              int* __restrict__ idxs) {
    __shared__ float2 lds[5120];
    float2* b1  = lds;
    float2* b2  = lds + 2048;
    float2* twl = lds + 4096;
    __shared__ float cv[2048];
    __shared__ float rv[256];
    __shared__ int ri[256];
    __shared__ float topv[TOPK];
    __shared__ int topi[TOPK];
    int tid = threadIdx.x;
    int b = blockIdx.x;
    const float* Sg = S + (size_t)b * NF * 2;
    for (int j = tid; j < 1024; j += 256) {
        float sn, cs;
        sincosf(6.283185307179586f * (float)j / 2048.0f, &sn, &cs);   // inverse sign
        twl[j] = make_float2(cs, sn);
    }
    __syncthreads();
    // fused Hermitian-extension load + radix-2 -> b1
#pragma unroll
    for (int h = 0; h < 2; h++) {
        int j0 = 2 * tid + 512 * h;
#pragma unroll
        for (int e = 0; e < 2; e++) {
            int j = j0 + e;
            float2 zl = make_float2(Sg[2 * j], Sg[2 * j + 1]);            // j <= 1023
            int fh = j + 1024;
            int ms = 2048 - fh;                                           // mirror for fh>1024
            float2 zh = (fh == 1024) ? make_float2(Sg[2048], Sg[2049])
                                     : make_float2(Sg[2 * ms], -Sg[2 * ms + 1]);
            b1[2 * j]     = cadd(zl, zh);
            b1[2 * j + 1] = cmul(csub(zl, zh), twl[j]);
        }
    }
    __syncthreads();
    fft_r4_chain<-1>(b1, b2, twl, tid);   // result in b2
    const float scale = 1.0f / ((float)LL * (float)DD);
    for (int f = tid; f < 2048; f += 256) cv[f] = b2[f].x * scale;
    __syncthreads();
    for (int r = 0; r < TOPK; r++) {
        float best = -3.0e38f;
        int bi = 0x7fffffff;
        for (int f = tid; f < 2048; f += 256) {
            bool taken = false;
            for (int q = 0; q < r; q++) taken |= (topi[q] == f);
            float v = cv[f];
            if (!taken && (v > best || (v == best && f < bi))) { best = v; bi = f; }
        }
        rv[tid] = best; ri[tid] = bi;
        __syncthreads();
        for (int s = 128; s > 0; s >>= 1) {
            if (tid < s) {
                float v2 = rv[tid + s]; int i2 = ri[tid + s];
                if (v2 > rv[tid] || (v2 == rv[tid] && i2 < ri[tid])) { rv[tid] = v2; ri[tid] = i2; }
            }
            __syncthreads();
        }
        if (tid == 0) { topv[r] = rv[0]; topi[r] = ri[0]; }
        __syncthreads();
    }
    if (tid == 0) {
        float mx = topv[0];
        float e[TOPK], sum = 0.f;
        for (int k = 0; k < TOPK; k++) { e[k] = expf(topv[k] - mx); sum += e[k]; }
        for (int k = 0; k < TOPK; k++) {
            wts[b * TOPK + k] = e[k] / sum;
            idxs[b * TOPK + k] = topi[k];
        }
    }
}

// ---------------------------------------------------------------------------
// XC[b,l,:] = round_bf16( sum_k w_k * XB[b,(l-idx_k)&2047,:] )
__global__ __launch_bounds__(128) void k_combine(const u16* __restrict__ XB,
                                                 const float* __restrict__ wts,
                                                 const int* __restrict__ idxs,
                                                 u16* __restrict__ XC) {
    int l = blockIdx.x, b = blockIdx.y;
    int t = threadIdx.x;
    const ushort4* Xb = (const ushort4*)(XB + (size_t)b * LL * DD);
    float4 acc = make_float4(0.f, 0.f, 0.f, 0.f);
#pragma unroll
    for (int k = 0; k < TOPK; k++) {
        float w = wts[b * TOPK + k];
        int r = (l - idxs[b * TOPK + k]) & (LL - 1);
        ushort4 v = Xb[(size_t)r * 128 + t];
        acc.x += w * bf2f(v.x); acc.y += w * bf2f(v.y);
        acc.z += w * bf2f(v.z); acc.w += w * bf2f(v.w);
    }
    ushort4 o;
    o.x = f2bf(acc.x); o.y = f2bf(acc.y); o.z = f2bf(acc.z); o.w = f2bf(acc.w);
    ((ushort4*)(XC + (size_t)b * LL * DD))[(size_t)l * 128 + t] = o;
}

// ---------------------------------------------------------------------------
extern "C" void kernel_launch(void* const* d_in, const int* in_sizes, int n_in,
                              void* d_out, int out_size, void* d_ws, size_t ws_size,
                              hipStream_t stream) {
    const float* x  = (const float*)d_in[0];
    const float* Wq = (const float*)d_in[1];
    const float* Wk = (const float*)d_in[3];
    const float* Wv = (const float*)d_in[5];
    const float* bv = (const float*)d_in[6];
    // bq, bk provably cancel (tau-independent shift; top-k & softmax shift-invariant)
    (void)in_sizes; (void)n_in; (void)out_size; (void)ws_size;

    float* ws  = (float*)d_ws;
    u16*   XB  = (u16*)(ws + OFF_XB);
    u16*   XTB = (u16*)(ws + OFF_XTB);
    u16*   GTB = (u16*)(ws + OFF_GTB);
    u16*   XC  = (u16*)(ws + OFF_XC);
    u16*   BM  = (u16*)(ws + OFF_BBM);
    float* S   = ws + OFF_S;
    float* wts = ws + OFF_W;
    int*   idx = (int*)(ws + OFF_I);
    float* out = (float*)d_out;

    k_pre<<<16704, 256, 0, stream>>>(x, Wq, Wk, Wv, XB, XTB, BM, S);
    k_gemm2<<<dim3((BB * LL) / 128, DD / 128), 256, 0, stream>>>(XB, BM, GTB);
    k_fft<<<dim3(64, BB), 256, 0, stream>>>(XTB, GTB, S);
    k_topk<<<BB, 256, 0, stream>>>(S, wts, idx);
    k_combine<<<dim3(LL, BB), 128, 0, stream>>>(XB, wts, idx, XC);
    k_gemm3<<<dim3((BB * LL) / 128, DD / 128), 256, 0, stream>>>(XC, BM, bv, out);
}